// Round 9
// baseline (128.159 us; speedup 1.0000x reference)
//
#include <hip/hip_runtime.h>
#include <stdint.h>

#define DEVI static __device__ __forceinline__

typedef unsigned short u16;
typedef short bf16x8 __attribute__((ext_vector_type(8)));
typedef u16 u16x8 __attribute__((ext_vector_type(8)));
typedef u16 u16x4 __attribute__((ext_vector_type(4)));
typedef float f32x4 __attribute__((ext_vector_type(4)));

// round-to-nearest-even float -> bf16
DEVI u16 f2bf(float f) {
    uint32_t u = __builtin_bit_cast(uint32_t, f);
    u += 0x7FFFu + ((u >> 16) & 1u);
    return (u16)(u >> 16);
}
DEVI float bf2f(u16 u) { return __builtin_bit_cast(float, (uint32_t)u << 16); }

struct GemmArgs {
    const void* A;            // A source per AMODE
    const void* A2;           // second A source (fused projections)
    long long aStrideBytes;   // per-batch stride in BYTES
    int lda;                  // elements
    const u16* Bm;            // [N x K] bf16 (B^T layout)
    long long bStrideElts;
    int ldb;
    int K;                    // per-block K length
    const float* bias; const float* bias2; const float* bias3;
    u16* outB;                // bf16 output
    float* outF;              // fp32 output
    long long outFStride;     // per-batch elements
    const float* qm; const float* md; const float* tauPtr; float scale;
    float* partials;          // [B*2048 * 16] row partial sums
    const float* invsPtr;     // [8192] 1/rowsum (read, AMODE2)
    float* invsOut;           // [8192] 1/rowsum (written by PV norm blocks)
    u16* vt;                  // V transposed dest [B][512][2048]
};

enum { EPI_PROJ3 = 0, EPI_LOGITS = 1, EPI_LOGITSB = 2, EPI_PV = 3, EPI_OUT = 4 };
// AMODE: 0 = bf16 A via global_load_lds, double-buffered prefetch pipeline;
//        1 = fp32 A reg-stage+convert (fallback); 2 = sum of two bf16 split-K
//        partials (+invs scale) reg-staged.

template <int EPI, int AMODE, int TM>
__global__ __launch_bounds__(256, 4) void gemm_bt(GemmArgs p) {
    constexpr int NF = (TM == 128) ? 4 : 2;
    __shared__ u16 As[2][TM * 32];
    __shared__ u16 Bs[2][128 * 32];
    __shared__ float redBuf[2][128];
    __shared__ float sInvLds[128];

    const int tid = threadIdx.x;
    const int lane = tid & 63;
    const int wave = tid >> 6;
    const int g = lane >> 4, lr = lane & 15;
    const int waveRowBase = (TM == 128) ? (wave >> 1) * 64 : 0;
    const int waveColBase = (TM == 128) ? (wave & 1) * 64 : wave * 32;
    const int z = blockIdx.z;
    const int rowBase = blockIdx.x * TM;
    const int colBase = blockIdx.y * 128;

    int batch = z, koff = 0;
    if constexpr (EPI == EPI_PV) { batch = z & 3; koff = (z >> 2) * p.K; }

    const char* Abase;
    const float* bias = p.bias;
    const u16* Bbase;
    if constexpr (EPI == EPI_PROJ3) {
        Abase = (const char*)(z == 0 ? p.A : p.A2);
        Bbase = p.Bm + (size_t)z * 512 * 512;
        bias = (z == 0) ? p.bias : (z == 1 ? p.bias2 : p.bias3);
    } else {
        Abase = (const char*)p.A + (size_t)batch * p.aStrideBytes + (size_t)koff * (AMODE == 1 ? 4 : 2);
        Bbase = p.Bm + (size_t)batch * p.bStrideElts + koff;
    }

    // ---- fused normalize + rowsum-inv blocks (PV big path, blockIdx.y==4) ----
    if constexpr (EPI == EPI_PV && AMODE == 0) {
        if (blockIdx.y == 4) {
            if (tid < 128) {
                const float* pp = p.partials + ((size_t)batch * 2048 + rowBase + tid) * 16;
                float s = 0.f;
                #pragma unroll
                for (int t = 0; t < 16; ++t) s += pp[t];
                float inv = 1.0f / s;
                sInvLds[tid] = inv;
                p.invsOut[batch * 2048 + rowBase + tid] = inv;  // both splits write same value
            }
            __syncthreads();
            const u16* e = (const u16*)Abase + (size_t)rowBase * 2048;
            float* attnOut = p.outF + (size_t)batch * p.outFStride + (size_t)rowBase * 2048 + koff;
            #pragma unroll 4
            for (int it = 0; it < 64; ++it) {
                int cc = it * 256 + tid;
                int row = cc >> 7, colc = (cc & 127) * 8;
                float s = sInvLds[row];
                u16x8 v = *(const u16x8*)(e + (size_t)row * 2048 + colc);
                f32x4 f0, f1;
                f0[0] = bf2f(v[0]) * s; f0[1] = bf2f(v[1]) * s;
                f0[2] = bf2f(v[2]) * s; f0[3] = bf2f(v[3]) * s;
                f1[0] = bf2f(v[4]) * s; f1[1] = bf2f(v[5]) * s;
                f1[2] = bf2f(v[6]) * s; f1[3] = bf2f(v[7]) * s;
                float* dst = attnOut + (size_t)row * 2048 + colc;
                __builtin_nontemporal_store(f0, (f32x4*)dst);
                __builtin_nontemporal_store(f1, (f32x4*)dst + 1);
            }
            return;
        }
    }

    f32x4 acc[4][NF] = {};

    const int nk = p.K >> 5;

    if constexpr (AMODE == 0) {
        // ---- double-buffered prefetch pipeline (raw barriers + own-wave vmcnt
        // drain BEFORE the barrier => block-wide completion guarantee) ----
        auto stage = [&](int buf, int kt) {
            const int kb = kt << 5;
            #pragma unroll
            for (int i = 0; i < TM / 64; ++i) {
                int c = i * 256 + tid;  // 16B chunks; row = c>>2, k-off = (c&3)*8
                const u16* gp = (const u16*)Abase + (size_t)(rowBase + (c >> 2)) * p.lda + kb + (c & 3) * 8;
                char* lp = (char*)&As[buf][0] + (i * 256 + wave * 64) * 16;  // wave-uniform base
                __builtin_amdgcn_global_load_lds((const __attribute__((address_space(1))) void*)gp,
                                                 (__attribute__((address_space(3))) void*)lp, 16, 0, 0);
            }
            #pragma unroll
            for (int i = 0; i < 2; ++i) {
                int c = i * 256 + tid;
                const u16* gp = Bbase + (size_t)(colBase + (c >> 2)) * p.ldb + kb + (c & 3) * 8;
                char* lp = (char*)&Bs[buf][0] + (i * 256 + wave * 64) * 16;
                __builtin_amdgcn_global_load_lds((const __attribute__((address_space(1))) void*)gp,
                                                 (__attribute__((address_space(3))) void*)lp, 16, 0, 0);
            }
        };
        stage(0, 0);
        asm volatile("s_waitcnt vmcnt(0)" ::: "memory");
        __builtin_amdgcn_s_barrier();
        for (int kt = 0; kt < nk; ++kt) {
            const int cur = kt & 1;
            if (kt + 1 < nk) stage(cur ^ 1, kt + 1);   // prefetch next tile
            bf16x8 af[4], bfr[NF];
            #pragma unroll
            for (int m = 0; m < 4; ++m)
                af[m] = *(const bf16x8*)&As[cur][(waveRowBase + m * 16 + lr) * 32 + g * 8];
            #pragma unroll
            for (int n = 0; n < NF; ++n)
                bfr[n] = *(const bf16x8*)&Bs[cur][(waveColBase + n * 16 + lr) * 32 + g * 8];
            __builtin_amdgcn_s_setprio(1);
            #pragma unroll
            for (int m = 0; m < 4; ++m)
                #pragma unroll
                for (int n = 0; n < NF; ++n)
                    acc[m][n] = __builtin_amdgcn_mfma_f32_16x16x32_bf16(af[m], bfr[n], acc[m][n], 0, 0, 0);
            __builtin_amdgcn_s_setprio(0);
            // own prefetch complete, then barrier => everyone's prefetch complete;
            // also fences reads of As[cur] before next iter overwrites it.
            asm volatile("s_waitcnt vmcnt(0)" ::: "memory");
            __builtin_amdgcn_s_barrier();
        }
    } else {
        // ---- fallback single-buffer structure (AMODE 1/2) ----
        const int arow2 = tid >> 2, kh2 = (tid & 3) << 3;
        const u16* pa0 = nullptr; const u16* pa1 = nullptr; float sInv = 1.0f;
        if constexpr (AMODE == 2) {
            pa0 = (const u16*)p.A + (size_t)(rowBase + arow2) * 512 + kh2;
            pa1 = pa0 + (size_t)8192 * 512;
            sInv = p.invsPtr ? p.invsPtr[rowBase + arow2] : 1.0f;
        }
        for (int kt = 0; kt < nk; ++kt) {
            const int kb = kt << 5;
            float4 areg[4]; u16x8 a0, a1;
            if constexpr (AMODE == 1) {
                const float* Af = (const float*)Abase;
                const int arow = tid >> 1, kh = (tid & 1) << 4;
                const float* src = Af + (size_t)(rowBase + arow) * p.lda + kb + kh;
                #pragma unroll
                for (int j = 0; j < 4; ++j) areg[j] = ((const float4*)src)[j];
            } else {
                a0 = *(const u16x8*)(pa0 + kb);
                a1 = *(const u16x8*)(pa1 + kb);
            }
            __syncthreads();   // previous tile fully consumed
            if constexpr (AMODE == 1) {
                const int arow = tid >> 1, kh = (tid & 1) << 4;
                u16 tmp[16];
                #pragma unroll
                for (int j = 0; j < 4; ++j) {
                    tmp[4 * j + 0] = f2bf(areg[j].x);
                    tmp[4 * j + 1] = f2bf(areg[j].y);
                    tmp[4 * j + 2] = f2bf(areg[j].z);
                    tmp[4 * j + 3] = f2bf(areg[j].w);
                }
                #pragma unroll
                for (int h = 0; h < 2; ++h)
                    *(u16x8*)&As[0][arow * 32 + kh + h * 8] = *(u16x8*)&tmp[h * 8];
            } else {
                u16 tmp[8];
                #pragma unroll
                for (int j = 0; j < 8; ++j)
                    tmp[j] = f2bf((bf2f(a0[j]) + bf2f(a1[j])) * sInv);
                *(u16x8*)&As[0][arow2 * 32 + kh2] = *(u16x8*)tmp;
            }
            #pragma unroll
            for (int i = 0; i < 2; ++i) {
                int c = i * 256 + tid;
                const u16* gp = Bbase + (size_t)(colBase + (c >> 2)) * p.ldb + kb + (c & 3) * 8;
                char* lp = (char*)&Bs[0][0] + (i * 256 + wave * 64) * 16;
                __builtin_amdgcn_global_load_lds((const __attribute__((address_space(1))) void*)gp,
                                                 (__attribute__((address_space(3))) void*)lp, 16, 0, 0);
            }
            __syncthreads();   // staging complete

            bf16x8 af[4], bfr[NF];
            #pragma unroll
            for (int m = 0; m < 4; ++m)
                af[m] = *(const bf16x8*)&As[0][(waveRowBase + m * 16 + lr) * 32 + g * 8];
            #pragma unroll
            for (int n = 0; n < NF; ++n)
                bfr[n] = *(const bf16x8*)&Bs[0][(waveColBase + n * 16 + lr) * 32 + g * 8];
            #pragma unroll
            for (int m = 0; m < 4; ++m)
                #pragma unroll
                for (int n = 0; n < NF; ++n)
                    acc[m][n] = __builtin_amdgcn_mfma_f32_16x16x32_bf16(af[m], bfr[n], acc[m][n], 0, 0, 0);
        }
    }

    // epilogue: element (m,n,i): row = rB + m*16 + g*4 + i, col = cB + n*16 + lr
    const int rB = rowBase + waveRowBase;
    const int cB = colBase + waveColBase;

    if constexpr (EPI == EPI_PROJ3) {
        if (z < 2) {
            u16* dst = p.outB + (size_t)z * 8192 * 512;
            #pragma unroll
            for (int n = 0; n < NF; ++n) {
                int col = cB + n * 16 + lr;
                float bv = bias[col];
                #pragma unroll
                for (int m = 0; m < 4; ++m) {
                    int r0 = rB + m * 16 + g * 4;
                    #pragma unroll
                    for (int i = 0; i < 4; ++i)
                        dst[(size_t)(r0 + i) * 512 + col] = f2bf(acc[m][n][i] + bv);
                }
            }
        } else {  // V projection, transposed store
            #pragma unroll
            for (int n = 0; n < NF; ++n) {
                int col = cB + n * 16 + lr;
                float bv = bias[col];
                #pragma unroll
                for (int m = 0; m < 4; ++m) {
                    int r0 = rB + m * 16 + g * 4;
                    int b = r0 >> 11, k0 = r0 & 2047;
                    u16x4 pk;
                    #pragma unroll
                    for (int i = 0; i < 4; ++i) pk[i] = f2bf(acc[m][n][i] + bv);
                    *(u16x4*)&p.vt[((size_t)b * 512 + col) * 2048 + k0] = pk;
                }
            }
        }
    } else if constexpr (EPI == EPI_LOGITS || EPI == EPI_LOGITSB) {
        const float* qmB = p.qm + z * 2048;
        const float* mdB = p.md + z * 2048;
        const float tau = *p.tauPtr;
        float* outRow = p.outF + (size_t)z * p.outFStride;
        float mdv[NF];
        #pragma unroll
        for (int n = 0; n < NF; ++n) mdv[n] = mdB[cB + n * 16 + lr];
        #pragma unroll
        for (int m = 0; m < 4; ++m) {
            int r0 = rB + m * 16 + g * 4;
            #pragma unroll
            for (int i = 0; i < 4; ++i) {
                int q = r0 + i;
                float qv = qmB[q];
                float rs = 0.f;
                #pragma unroll
                for (int n = 0; n < NF; ++n) {
                    float t = tau * (qv + mdv[n]);
                    float u = 1.0f / (1.0f + __expf(-t));
                    u = fminf(fmaxf(u, 1e-6f), 1e6f);
                    float e = __expf(acc[m][n][i] * p.scale * u);
                    if (EPI == EPI_LOGITSB)
                        p.outB[((size_t)(z * 2048 + q)) * 2048 + cB + n * 16 + lr] = f2bf(e);
                    else
                        outRow[(size_t)q * 2048 + cB + n * 16 + lr] = e;
                    rs += e;
                }
                #pragma unroll
                for (int off = 1; off < 16; off <<= 1) rs += __shfl_xor(rs, off, 64);
                if (lr == 0) redBuf[wave & 1][waveRowBase + m * 16 + g * 4 + i] = rs;
            }
        }
        __syncthreads();
        if (tid < 128) {
            float s = redBuf[0][tid] + redBuf[1][tid];
            int q = rowBase + tid;
            p.partials[((size_t)z * 2048 + q) * 16 + blockIdx.y] = s;
        }
    } else if constexpr (EPI == EPI_PV) {
        const int split = z >> 2;
        u16* dst = p.outB + (size_t)split * 8192 * 512;
        #pragma unroll
        for (int n = 0; n < NF; ++n) {
            int col = cB + n * 16 + lr;
            #pragma unroll
            for (int m = 0; m < 4; ++m) {
                int r0 = rB + m * 16 + g * 4;
                size_t gr = (size_t)batch * 2048 + r0;
                #pragma unroll
                for (int i = 0; i < 4; ++i)
                    dst[(gr + i) * 512 + col] = f2bf(acc[m][n][i]);
            }
        }
    } else {  // EPI_OUT (nontemporal: out is never re-read)
        #pragma unroll
        for (int n = 0; n < NF; ++n) {
            int col = cB + n * 16 + lr;
            float bv = p.bias[col];
            #pragma unroll
            for (int m = 0; m < 4; ++m) {
                int r0 = rB + m * 16 + g * 4;
                #pragma unroll
                for (int i = 0; i < 4; ++i)
                    __builtin_nontemporal_store(acc[m][n][i] + bv, &p.outF[(size_t)(r0 + i) * 512 + col]);
            }
        }
    }
}

// convert weights (4x 512x512, contiguous dst) + query/key feats to bf16.
__global__ void cvt_all2(const float* Wq, const float* Wk, const float* Wv, const float* Wo,
                         const float* qf, const float* kf,
                         u16* wdst, u16* qdst, u16* kdst) {
    const size_t WSZ = (size_t)512 * 512;
    const size_t FSZ = (size_t)8192 * 512;
    size_t i = ((size_t)blockIdx.x * 256 + threadIdx.x) * 4;
    const float* src; u16* dstp;
    if (i < 4 * WSZ) {
        int w = (int)(i / WSZ);
        src = (w == 0 ? Wq : w == 1 ? Wk : w == 2 ? Wv : Wo) + (i - (size_t)w * WSZ);
        dstp = wdst + i;
    } else if (i < 4 * WSZ + FSZ) {
        size_t off = i - 4 * WSZ;
        src = qf + off; dstp = qdst + off;
    } else {
        size_t off = i - 4 * WSZ - FSZ;
        src = kf + off; dstp = kdst + off;
    }
    float4 v = *(const float4*)src;
    u16x4 u = { f2bf(v.x), f2bf(v.y), f2bf(v.z), f2bf(v.w) };
    *(u16x4*)dstp = u;
}

__global__ void rowsum_inv(const float* __restrict__ partials, float* __restrict__ invs) {
    int r = blockIdx.x * 256 + threadIdx.x;  // 8192 rows
    float s = 0.f;
    #pragma unroll
    for (int t = 0; t < 16; ++t) s += partials[r * 16 + t];
    invs[r] = 1.0f / s;
}

// fp32-e in-place normalize (small-ws fallback path)
__global__ void normalize_attn(float* __restrict__ attn, const float* __restrict__ invs) {
    size_t i4 = (size_t)blockIdx.x * 256 + threadIdx.x;  // 4 floats per thread
    int row = (int)(i4 >> 9);
    float s = invs[row];
    float4 v = ((const float4*)attn)[i4];
    v.x *= s; v.y *= s; v.z *= s; v.w *= s;
    ((float4*)attn)[i4] = v;
}

extern "C" void kernel_launch(void* const* d_in, const int* in_sizes, int n_in,
                              void* d_out, int out_size, void* d_ws, size_t ws_size,
                              hipStream_t stream) {
    const float* qf  = (const float*)d_in[0];
    const float* kf  = (const float*)d_in[1];
    const float* qm  = (const float*)d_in[2];
    const float* md  = (const float*)d_in[3];
    const float* Wq  = (const float*)d_in[4];
    const float* bq  = (const float*)d_in[5];
    const float* Wk  = (const float*)d_in[6];
    const float* bk  = (const float*)d_in[7];
    const float* Wv  = (const float*)d_in[8];
    const float* bv  = (const float*)d_in[9];
    const float* Wo  = (const float*)d_in[10];
    const float* bo  = (const float*)d_in[11];
    const float* tau = (const float*)d_in[12];

    float* out  = (float*)d_out;                       // [4,2048,512]
    float* attn = out + (size_t)4 * 2048 * 512;        // [4,2048,2048]

    const size_t NV = (size_t)8192 * 512;
    u16* Qb   = (u16*)d_ws;                            // [8192,512] bf16
    u16* Kb   = Qb + NV;
    u16* Vtb  = Kb + NV;                               // [4][512][2048]
    u16* Wqb  = Vtb + NV;                              // Wq,Wk,Wv,Wo bf16 contiguous
    u16* Wob  = Wqb + (size_t)3 * 512 * 512;
    float* partials = (float*)(Wqb + (size_t)4 * 512 * 512);  // [8192,16]
    float* invs = partials + (size_t)8192 * 16;
    u16* attE = (u16*)(invs + 8192);                   // [4,2048,2048] bf16 (big path)
    u16* qfB  = attE + (size_t)4 * 2048 * 2048;        // [8192,512] bf16
    u16* kfB  = qfB + NV;
    size_t need = (size_t)((char*)(kfB + NV) - (char*)d_ws);
    const bool big = ws_size >= need;

    u16* partialPV = Qb;   // aliases Qb+Kb (dead after logits): [2][8192][512] bf16

    dim3 blk(256);

    GemmArgs a = {};
    a.lda = 512; a.ldb = 512; a.K = 512;
    a.bias = bq; a.bias2 = bk; a.bias3 = bv;
    a.outB = Qb; a.vt = Vtb;
    if (big) {
        // convert weights + feats to bf16, then fully-async projections
        cvt_all2<<<dim3(9216), blk, 0, stream>>>(Wq, Wk, Wv, Wo, qf, kf, Wqb, qfB, kfB);
        a.A = qfB; a.A2 = kfB; a.Bm = Wqb;
        gemm_bt<EPI_PROJ3, 0, 128><<<dim3(64, 4, 3), blk, 0, stream>>>(a);
    } else {
        cvt_all2<<<dim3(1024), blk, 0, stream>>>(Wq, Wk, Wv, Wo, qf, kf, Wqb, nullptr, nullptr);
        a.A = qf; a.A2 = kf; a.Bm = Wqb;
        gemm_bt<EPI_PROJ3, 1, 128><<<dim3(64, 4, 3), blk, 0, stream>>>(a);
    }

    // logits: e = exp((Q K^T)/sqrt(H) * u), per-tile row partial sums
    GemmArgs lg = {};
    lg.A = Qb; lg.aStrideBytes = (long long)2048 * 512 * 2; lg.lda = 512;
    lg.Bm = Kb; lg.bStrideElts = (long long)2048 * 512; lg.ldb = 512;
    lg.K = 512;
    lg.qm = qm; lg.md = md; lg.tauPtr = tau;
    lg.scale = 0.04419417382415922f;  // 1/sqrt(512)
    lg.partials = partials;
    if (big) {
        lg.outB = attE;
        gemm_bt<EPI_LOGITSB, 0, 128><<<dim3(16, 16, 4), blk, 0, stream>>>(lg);
    } else {
        lg.outF = attn; lg.outFStride = (long long)2048 * 2048;
        gemm_bt<EPI_LOGITS, 0, 128><<<dim3(16, 16, 4), blk, 0, stream>>>(lg);
    }

    // att_partial[split] = e[., split*1024 : +1024] @ V  (split-K=2)
    // big path: blockIdx.y==4 blocks compute invs + write normalized fp32 attn
    GemmArgs pv = {};
    pv.Bm = Vtb; pv.bStrideElts = (long long)512 * 2048; pv.ldb = 2048;
    pv.K = 1024; pv.outB = partialPV; pv.lda = 2048;
    pv.partials = partials; pv.invsOut = invs;
    if (big) {
        pv.A = attE; pv.aStrideBytes = (long long)2048 * 2048 * 2;
        pv.outF = attn; pv.outFStride = (long long)2048 * 2048;
        gemm_bt<EPI_PV, 0, 128><<<dim3(16, 5, 8), blk, 0, stream>>>(pv);
    } else {
        rowsum_inv<<<dim3(32), blk, 0, stream>>>(partials, invs);
        normalize_attn<<<dim3(16384), blk, 0, stream>>>(attn, invs);
        pv.A = attn; pv.aStrideBytes = (long long)2048 * 2048 * 4;
        gemm_bt<EPI_PV, 1, 128><<<dim3(16, 4, 8), blk, 0, stream>>>(pv);
    }

    // out = (partial0 + partial1)*invs @ Wo^T + bo  (reduce fused into A-stage)
    GemmArgs og = {};
    og.A = partialPV; og.lda = 512;
    og.Bm = Wob; og.ldb = 512;
    og.K = 512; og.bias = bo; og.outF = out;
    og.invsPtr = big ? invs : nullptr;
    gemm_bt<EPI_OUT, 2, 64><<<dim3(128, 4, 1), blk, 0, stream>>>(og);
}

// Round 10
// 123.963 us; speedup vs baseline: 1.0338x; 1.0338x over previous
//
#include <hip/hip_runtime.h>
#include <stdint.h>

#define DEVI static __device__ __forceinline__

typedef unsigned short u16;
typedef short bf16x8 __attribute__((ext_vector_type(8)));
typedef u16 u16x8 __attribute__((ext_vector_type(8)));
typedef u16 u16x4 __attribute__((ext_vector_type(4)));
typedef float f32x4 __attribute__((ext_vector_type(4)));

// round-to-nearest-even float -> bf16
DEVI u16 f2bf(float f) {
    uint32_t u = __builtin_bit_cast(uint32_t, f);
    u += 0x7FFFu + ((u >> 16) & 1u);
    return (u16)(u >> 16);
}
DEVI float bf2f(u16 u) { return __builtin_bit_cast(float, (uint32_t)u << 16); }

struct GemmArgs {
    const void* A;            // A source per AMODE
    const void* A2;           // second A source (fused projections)
    long long aStrideBytes;   // per-batch stride in BYTES
    int lda;                  // elements
    const u16* Bm;            // [N x K] bf16 (B^T layout)
    long long bStrideElts;
    int ldb;
    int K;                    // per-block K length
    const float* bias; const float* bias2; const float* bias3;
    u16* outB;                // bf16 output
    float* outF;              // fp32 output
    long long outFStride;     // per-batch elements
    const float* qm; const float* md; const float* tauPtr; float scale;
    // for LOGITS epilogue, qm/md carry eq = exp(-tau*qm), em = exp(-tau*md)
    float* partials;          // [B*2048 * 16] row partial sums
    const float* invsPtr;     // [8192] 1/rowsum (read, AMODE2)
    float* invsOut;           // [8192] 1/rowsum (written by PV norm blocks)
    u16* vt;                  // V transposed dest [B][512][2048]
};

enum { EPI_PROJ3 = 0, EPI_LOGITS = 1, EPI_LOGITSB = 2, EPI_PV = 3, EPI_OUT = 4 };
// AMODE: 0 = bf16 A via global_load_lds; 1 = fp32 A reg-stage+convert; 2 = sum of two
// bf16 split-K partials (+invs scale) reg-staged.
// U2: stage 2 BK=32 tiles per barrier pair (32 MFMA per vmcnt drain). AMODE=0 only.

template <int EPI, int AMODE, int TM, bool U2>
__global__ __launch_bounds__(256, 4) void gemm_bt(GemmArgs p) {
    constexpr int NB = U2 ? 2 : 1;
    constexpr int NF = (TM == 128) ? 4 : 2;
    __shared__ u16 As[NB][TM * 32];
    __shared__ u16 Bs[NB][128 * 32];
    __shared__ float redBuf[2][128];
    __shared__ float sInvLds[128];

    const int tid = threadIdx.x;
    const int lane = tid & 63;
    const int wave = tid >> 6;
    const int g = lane >> 4, lr = lane & 15;
    const int waveRowBase = (TM == 128) ? (wave >> 1) * 64 : 0;
    const int waveColBase = (TM == 128) ? (wave & 1) * 64 : wave * 32;
    const int z = blockIdx.z;
    const int rowBase = blockIdx.x * TM;
    const int colBase = blockIdx.y * 128;

    int batch = z, koff = 0;
    if constexpr (EPI == EPI_PV) { batch = z & 3; koff = (z >> 2) * p.K; }

    const char* Abase;
    const float* bias = p.bias;
    const u16* Bbase;
    if constexpr (EPI == EPI_PROJ3) {
        Abase = (const char*)(z == 0 ? p.A : p.A2);
        Bbase = p.Bm + (size_t)z * 512 * 512;
        bias = (z == 0) ? p.bias : (z == 1 ? p.bias2 : p.bias3);
    } else {
        Abase = (const char*)p.A + (size_t)batch * p.aStrideBytes + (size_t)koff * (AMODE == 1 ? 4 : 2);
        Bbase = p.Bm + (size_t)batch * p.bStrideElts + koff;
    }

    // ---- fused normalize + rowsum-inv blocks (PV big path, blockIdx.y==4) ----
    if constexpr (EPI == EPI_PV && AMODE == 0) {
        if (blockIdx.y == 4) {
            // 1/rowsum for rows [rowBase,+128)
            if (tid < 128) {
                const float* pp = p.partials + ((size_t)batch * 2048 + rowBase + tid) * 16;
                float s = 0.f;
                #pragma unroll
                for (int t = 0; t < 16; ++t) s += pp[t];
                float inv = 1.0f / s;
                sInvLds[tid] = inv;
                p.invsOut[batch * 2048 + rowBase + tid] = inv;  // both splits write same value
            }
            __syncthreads();
            const u16* e = (const u16*)Abase + (size_t)rowBase * 2048;
            float* attnOut = p.outF + (size_t)batch * p.outFStride + (size_t)rowBase * 2048 + koff;
            #pragma unroll 4
            for (int it = 0; it < 64; ++it) {
                int cc = it * 256 + tid;
                int row = cc >> 7, colc = (cc & 127) * 8;
                float s = sInvLds[row];
                u16x8 v = *(const u16x8*)(e + (size_t)row * 2048 + colc);
                f32x4 f0, f1;
                f0[0] = bf2f(v[0]) * s; f0[1] = bf2f(v[1]) * s;
                f0[2] = bf2f(v[2]) * s; f0[3] = bf2f(v[3]) * s;
                f1[0] = bf2f(v[4]) * s; f1[1] = bf2f(v[5]) * s;
                f1[2] = bf2f(v[6]) * s; f1[3] = bf2f(v[7]) * s;
                float* dst = attnOut + (size_t)row * 2048 + colc;
                __builtin_nontemporal_store(f0, (f32x4*)dst);
                __builtin_nontemporal_store(f1, (f32x4*)dst + 1);
            }
            return;
        }
    }

    f32x4 acc[4][NF] = {};

    // AMODE==2 invariants (hoisted)
    const int arow2 = tid >> 2, kh2 = (tid & 3) << 3;
    const u16* pa0 = nullptr; const u16* pa1 = nullptr; float sInv = 1.0f;
    if constexpr (AMODE == 2) {
        pa0 = (const u16*)p.A + (size_t)(rowBase + arow2) * 512 + kh2;
        pa1 = pa0 + (size_t)8192 * 512;
        sInv = p.invsPtr ? p.invsPtr[rowBase + arow2] : 1.0f;
    }

    const int nk = p.K >> 5;
    for (int kt = 0; kt < nk; kt += NB) {
        const int kb = kt << 5;
        float4 areg[4]; u16x8 a0, a1;
        if constexpr (AMODE == 1) {
            const float* Af = (const float*)Abase;
            const int arow = tid >> 1, kh = (tid & 1) << 4;
            const float* src = Af + (size_t)(rowBase + arow) * p.lda + kb + kh;
            #pragma unroll
            for (int j = 0; j < 4; ++j) areg[j] = ((const float4*)src)[j];
        } else if constexpr (AMODE == 2) {
            a0 = *(const u16x8*)(pa0 + kb);
            a1 = *(const u16x8*)(pa1 + kb);
        }
        __syncthreads();   // previous tiles fully consumed
        if constexpr (AMODE == 1) {
            const int arow = tid >> 1, kh = (tid & 1) << 4;
            u16 tmp[16];
            #pragma unroll
            for (int j = 0; j < 4; ++j) {
                tmp[4 * j + 0] = f2bf(areg[j].x);
                tmp[4 * j + 1] = f2bf(areg[j].y);
                tmp[4 * j + 2] = f2bf(areg[j].z);
                tmp[4 * j + 3] = f2bf(areg[j].w);
            }
            #pragma unroll
            for (int h = 0; h < 2; ++h)
                *(u16x8*)&As[0][arow * 32 + kh + h * 8] = *(u16x8*)&tmp[h * 8];
        } else if constexpr (AMODE == 2) {
            u16 tmp[8];
            #pragma unroll
            for (int j = 0; j < 8; ++j)
                tmp[j] = f2bf((bf2f(a0[j]) + bf2f(a1[j])) * sInv);
            *(u16x8*)&As[0][arow2 * 32 + kh2] = *(u16x8*)tmp;
        } else {
            #pragma unroll
            for (int b = 0; b < NB; ++b)
                #pragma unroll
                for (int i = 0; i < TM / 64; ++i) {
                    int c = i * 256 + tid;  // 16B chunks; row = c>>2, k-off = (c&3)*8
                    const u16* gp = (const u16*)Abase + (size_t)(rowBase + (c >> 2)) * p.lda + kb + b * 32 + (c & 3) * 8;
                    char* lp = (char*)&As[b][0] + (i * 256 + wave * 64) * 16;  // wave-uniform base
                    __builtin_amdgcn_global_load_lds((const __attribute__((address_space(1))) void*)gp,
                                                     (__attribute__((address_space(3))) void*)lp, 16, 0, 0);
                }
        }
        #pragma unroll
        for (int b = 0; b < NB; ++b)
            #pragma unroll
            for (int i = 0; i < 2; ++i) {
                int c = i * 256 + tid;
                const u16* gp = Bbase + (size_t)(colBase + (c >> 2)) * p.ldb + kb + b * 32 + (c & 3) * 8;
                char* lp = (char*)&Bs[b][0] + (i * 256 + wave * 64) * 16;
                __builtin_amdgcn_global_load_lds((const __attribute__((address_space(1))) void*)gp,
                                                 (__attribute__((address_space(3))) void*)lp, 16, 0, 0);
            }
        __syncthreads();   // staging complete (vmcnt drained by barrier)

        #pragma unroll
        for (int b = 0; b < NB; ++b) {
            bf16x8 af[4], bfr[NF];
            #pragma unroll
            for (int m = 0; m < 4; ++m)
                af[m] = *(const bf16x8*)&As[b][(waveRowBase + m * 16 + lr) * 32 + g * 8];
            #pragma unroll
            for (int n = 0; n < NF; ++n)
                bfr[n] = *(const bf16x8*)&Bs[b][(waveColBase + n * 16 + lr) * 32 + g * 8];
            #pragma unroll
            for (int m = 0; m < 4; ++m)
                #pragma unroll
                for (int n = 0; n < NF; ++n)
                    acc[m][n] = __builtin_amdgcn_mfma_f32_16x16x32_bf16(af[m], bfr[n], acc[m][n], 0, 0, 0);
        }
    }

    // epilogue: element (m,n,i): row = rB + m*16 + g*4 + i, col = cB + n*16 + lr
    const int rB = rowBase + waveRowBase;
    const int cB = colBase + waveColBase;

    if constexpr (EPI == EPI_PROJ3) {
        if (z < 2) {
            u16* dst = p.outB + (size_t)z * 8192 * 512;
            #pragma unroll
            for (int n = 0; n < NF; ++n) {
                int col = cB + n * 16 + lr;
                float bv = bias[col];
                #pragma unroll
                for (int m = 0; m < 4; ++m) {
                    int r0 = rB + m * 16 + g * 4;
                    #pragma unroll
                    for (int i = 0; i < 4; ++i)
                        dst[(size_t)(r0 + i) * 512 + col] = f2bf(acc[m][n][i] + bv);
                }
            }
        } else {  // V projection, transposed store
            #pragma unroll
            for (int n = 0; n < NF; ++n) {
                int col = cB + n * 16 + lr;
                float bv = bias[col];
                #pragma unroll
                for (int m = 0; m < 4; ++m) {
                    int r0 = rB + m * 16 + g * 4;
                    int b = r0 >> 11, k0 = r0 & 2047;
                    u16x4 pk;
                    #pragma unroll
                    for (int i = 0; i < 4; ++i) pk[i] = f2bf(acc[m][n][i] + bv);
                    *(u16x4*)&p.vt[((size_t)b * 512 + col) * 2048 + k0] = pk;
                }
            }
        }
    } else if constexpr (EPI == EPI_LOGITS || EPI == EPI_LOGITSB) {
        // u = sigmoid(tau*(qm+md)) = 1/(1 + eq*em), eq/em precomputed (rank-1)
        const float* eqB = p.qm + z * 2048;
        const float* emB = p.md + z * 2048;
        float* outRow = p.outF + (size_t)z * p.outFStride;
        float emv[NF];
        #pragma unroll
        for (int n = 0; n < NF; ++n) emv[n] = emB[cB + n * 16 + lr];
        #pragma unroll
        for (int m = 0; m < 4; ++m) {
            int r0 = rB + m * 16 + g * 4;
            #pragma unroll
            for (int i = 0; i < 4; ++i) {
                int q = r0 + i;
                float eqv = eqB[q];
                float rs = 0.f;
                #pragma unroll
                for (int n = 0; n < NF; ++n) {
                    float u = 1.0f / (1.0f + eqv * emv[n]);
                    u = fmaxf(u, 1e-6f);
                    float e = __expf(acc[m][n][i] * p.scale * u);
                    if (EPI == EPI_LOGITSB)
                        p.outB[((size_t)(z * 2048 + q)) * 2048 + cB + n * 16 + lr] = f2bf(e);
                    else
                        outRow[(size_t)q * 2048 + cB + n * 16 + lr] = e;
                    rs += e;
                }
                #pragma unroll
                for (int off = 1; off < 16; off <<= 1) rs += __shfl_xor(rs, off, 64);
                if (lr == 0) redBuf[wave & 1][waveRowBase + m * 16 + g * 4 + i] = rs;
            }
        }
        __syncthreads();
        if (tid < 128) {
            float s = redBuf[0][tid] + redBuf[1][tid];
            int q = rowBase + tid;
            p.partials[((size_t)z * 2048 + q) * 16 + blockIdx.y] = s;
        }
    } else if constexpr (EPI == EPI_PV) {
        const int split = z >> 2;
        u16* dst = p.outB + (size_t)split * 8192 * 512;
        #pragma unroll
        for (int n = 0; n < NF; ++n) {
            int col = cB + n * 16 + lr;
            #pragma unroll
            for (int m = 0; m < 4; ++m) {
                int r0 = rB + m * 16 + g * 4;
                size_t gr = (size_t)batch * 2048 + r0;
                #pragma unroll
                for (int i = 0; i < 4; ++i)
                    dst[(gr + i) * 512 + col] = f2bf(acc[m][n][i]);
            }
        }
    } else {  // EPI_OUT (nontemporal: out is never re-read)
        #pragma unroll
        for (int n = 0; n < NF; ++n) {
            int col = cB + n * 16 + lr;
            float bv = p.bias[col];
            #pragma unroll
            for (int m = 0; m < 4; ++m) {
                int r0 = rB + m * 16 + g * 4;
                #pragma unroll
                for (int i = 0; i < 4; ++i)
                    __builtin_nontemporal_store(acc[m][n][i] + bv, &p.outF[(size_t)(r0 + i) * 512 + col]);
            }
        }
    }
}

// convert weights (4x 512x512) [+ qf/kf feats] to bf16; last 64 blocks compute
// eq = exp(-tau*qm), em = exp(-tau*md) (rank-1 sigmoid factors).
__global__ void cvt_all3(const float* Wq, const float* Wk, const float* Wv, const float* Wo,
                         const float* qf, const float* kf,
                         const float* qm, const float* md, const float* tauPtr,
                         u16* wdst, u16* qdst, u16* kdst,
                         float* eq, float* em) {
    if (blockIdx.x >= gridDim.x - 64) {
        int j = (blockIdx.x - (gridDim.x - 64)) * 256 + threadIdx.x;  // [0,16384)
        float tau = *tauPtr;
        if (j < 8192) eq[j] = __expf(-tau * qm[j]);
        else          em[j - 8192] = __expf(-tau * md[j - 8192]);
        return;
    }
    const size_t WSZ = (size_t)512 * 512;
    const size_t FSZ = (size_t)8192 * 512;
    size_t i = ((size_t)blockIdx.x * 256 + threadIdx.x) * 4;
    const float* src; u16* dstp;
    if (i < 4 * WSZ) {
        int w = (int)(i / WSZ);
        src = (w == 0 ? Wq : w == 1 ? Wk : w == 2 ? Wv : Wo) + (i - (size_t)w * WSZ);
        dstp = wdst + i;
    } else if (i < 4 * WSZ + FSZ) {
        size_t off = i - 4 * WSZ;
        src = qf + off; dstp = qdst + off;
    } else {
        size_t off = i - 4 * WSZ - FSZ;
        src = kf + off; dstp = kdst + off;
    }
    float4 v = *(const float4*)src;
    u16x4 u = { f2bf(v.x), f2bf(v.y), f2bf(v.z), f2bf(v.w) };
    *(u16x4*)dstp = u;
}

__global__ void rowsum_inv(const float* __restrict__ partials, float* __restrict__ invs) {
    int r = blockIdx.x * 256 + threadIdx.x;  // 8192 rows
    float s = 0.f;
    #pragma unroll
    for (int t = 0; t < 16; ++t) s += partials[r * 16 + t];
    invs[r] = 1.0f / s;
}

// fp32-e in-place normalize (small-ws fallback path)
__global__ void normalize_attn(float* __restrict__ attn, const float* __restrict__ invs) {
    size_t i4 = (size_t)blockIdx.x * 256 + threadIdx.x;  // 4 floats per thread
    int row = (int)(i4 >> 9);
    float s = invs[row];
    float4 v = ((const float4*)attn)[i4];
    v.x *= s; v.y *= s; v.z *= s; v.w *= s;
    ((float4*)attn)[i4] = v;
}

extern "C" void kernel_launch(void* const* d_in, const int* in_sizes, int n_in,
                              void* d_out, int out_size, void* d_ws, size_t ws_size,
                              hipStream_t stream) {
    const float* qf  = (const float*)d_in[0];
    const float* kf  = (const float*)d_in[1];
    const float* qm  = (const float*)d_in[2];
    const float* md  = (const float*)d_in[3];
    const float* Wq  = (const float*)d_in[4];
    const float* bq  = (const float*)d_in[5];
    const float* Wk  = (const float*)d_in[6];
    const float* bk  = (const float*)d_in[7];
    const float* Wv  = (const float*)d_in[8];
    const float* bv  = (const float*)d_in[9];
    const float* Wo  = (const float*)d_in[10];
    const float* bo  = (const float*)d_in[11];
    const float* tau = (const float*)d_in[12];

    float* out  = (float*)d_out;                       // [4,2048,512]
    float* attn = out + (size_t)4 * 2048 * 512;        // [4,2048,2048]

    const size_t NV = (size_t)8192 * 512;
    u16* Qb   = (u16*)d_ws;                            // [8192,512] bf16
    u16* Kb   = Qb + NV;
    u16* Vtb  = Kb + NV;                               // [4][512][2048]
    u16* Wqb  = Vtb + NV;                              // Wq,Wk,Wv,Wo bf16 contiguous
    u16* Wob  = Wqb + (size_t)3 * 512 * 512;
    float* partials = (float*)(Wqb + (size_t)4 * 512 * 512);  // [8192,16]
    float* invs = partials + (size_t)8192 * 16;
    float* eq = invs + 8192;                           // [8192] exp(-tau*qm)
    float* em = eq + 8192;                             // [8192] exp(-tau*md)
    u16* attE = (u16*)(em + 8192);                     // [4,2048,2048] bf16 (big path)
    u16* qfB  = attE + (size_t)4 * 2048 * 2048;        // [8192,512] bf16
    u16* kfB  = qfB + NV;
    size_t need = (size_t)((char*)(kfB + NV) - (char*)d_ws);
    const bool big = ws_size >= need;

    u16* partialPV = Qb;   // aliases Qb+Kb (dead after logits): [2][8192][512] bf16

    dim3 blk(256);

    GemmArgs a = {};
    a.lda = 512; a.ldb = 512; a.K = 512;
    a.bias = bq; a.bias2 = bk; a.bias3 = bv;
    a.outB = Qb; a.vt = Vtb;
    if (big) {
        // convert weights + feats to bf16 (+ eq/em), then fully-async projections
        cvt_all3<<<dim3(9280), blk, 0, stream>>>(Wq, Wk, Wv, Wo, qf, kf, qm, md, tau,
                                                 Wqb, qfB, kfB, eq, em);
        a.A = qfB; a.A2 = kfB; a.Bm = Wqb;
        gemm_bt<EPI_PROJ3, 0, 128, true><<<dim3(64, 4, 3), blk, 0, stream>>>(a);
    } else {
        cvt_all3<<<dim3(1088), blk, 0, stream>>>(Wq, Wk, Wv, Wo, qf, kf, qm, md, tau,
                                                 Wqb, nullptr, nullptr, eq, em);
        a.A = qf; a.A2 = kf; a.Bm = Wqb;
        gemm_bt<EPI_PROJ3, 1, 128, false><<<dim3(64, 4, 3), blk, 0, stream>>>(a);
    }

    // logits: e = exp((Q K^T)/sqrt(H) * u), u = 1/(1+eq*em); per-tile row partials
    GemmArgs lg = {};
    lg.A = Qb; lg.aStrideBytes = (long long)2048 * 512 * 2; lg.lda = 512;
    lg.Bm = Kb; lg.bStrideElts = (long long)2048 * 512; lg.ldb = 512;
    lg.K = 512;
    lg.qm = eq; lg.md = em; lg.tauPtr = tau;
    lg.scale = 0.04419417382415922f;  // 1/sqrt(512)
    lg.partials = partials;
    if (big) {
        lg.outB = attE;
        gemm_bt<EPI_LOGITSB, 0, 128, true><<<dim3(16, 16, 4), blk, 0, stream>>>(lg);
    } else {
        lg.outF = attn; lg.outFStride = (long long)2048 * 2048;
        gemm_bt<EPI_LOGITS, 0, 128, true><<<dim3(16, 16, 4), blk, 0, stream>>>(lg);
    }

    // att_partial[split] = e[., split*1024 : +1024] @ V  (split-K=2)
    // big path: blockIdx.y==4 blocks compute invs + write normalized fp32 attn
    GemmArgs pv = {};
    pv.Bm = Vtb; pv.bStrideElts = (long long)512 * 2048; pv.ldb = 2048;
    pv.K = 1024; pv.outB = partialPV; pv.lda = 2048;
    pv.partials = partials; pv.invsOut = invs;
    if (big) {
        pv.A = attE; pv.aStrideBytes = (long long)2048 * 2048 * 2;
        pv.outF = attn; pv.outFStride = (long long)2048 * 2048;
        gemm_bt<EPI_PV, 0, 128, true><<<dim3(16, 5, 8), blk, 0, stream>>>(pv);
    } else {
        rowsum_inv<<<dim3(32), blk, 0, stream>>>(partials, invs);
        normalize_attn<<<dim3(16384), blk, 0, stream>>>(attn, invs);
        pv.A = attn; pv.aStrideBytes = (long long)2048 * 2048 * 4;
        gemm_bt<EPI_PV, 1, 128, false><<<dim3(16, 4, 8), blk, 0, stream>>>(pv);
    }

    // out = (partial0 + partial1)*invs @ Wo^T + bo  (reduce fused into A-stage)
    GemmArgs og = {};
    og.A = partialPV; og.lda = 512;
    og.Bm = Wob; og.ldb = 512;
    og.K = 512; og.bias = bo; og.outF = out;
    og.invsPtr = big ? invs : nullptr;
    gemm_bt<EPI_OUT, 2, 64, false><<<dim3(128, 4, 1), blk, 0, stream>>>(og);
}

// Round 11
// 123.266 us; speedup vs baseline: 1.0397x; 1.0057x over previous
//
#include <hip/hip_runtime.h>
#include <stdint.h>

#define DEVI static __device__ __forceinline__

typedef unsigned short u16;
typedef short bf16x8 __attribute__((ext_vector_type(8)));
typedef u16 u16x8 __attribute__((ext_vector_type(8)));
typedef u16 u16x4 __attribute__((ext_vector_type(4)));
typedef float f32x4 __attribute__((ext_vector_type(4)));

// round-to-nearest-even float -> bf16
DEVI u16 f2bf(float f) {
    uint32_t u = __builtin_bit_cast(uint32_t, f);
    u += 0x7FFFu + ((u >> 16) & 1u);
    return (u16)(u >> 16);
}
DEVI float bf2f(u16 u) { return __builtin_bit_cast(float, (uint32_t)u << 16); }

// XCD-aware bijective chunk remap: consecutive hardware block ids (round-robin
// across the 8 XCDs) are remapped so each XCD owns one CONTIGUOUS logical tile
// range -> operand panels stay resident in that XCD's private L2.
// Requires nwg % 8 == 0 (all our grids satisfy this).
DEVI void xcd_remap(int& bx, int& by, int& bz, bool yfast) {
    int nx = gridDim.x, ny = gridDim.y, nz = gridDim.z;
    int nwg = nx * ny * nz;
    if (nwg & 7) return;
    int f = yfast ? (by + ny * (bx + nx * bz))
                  : (bx + nx * (by + ny * bz));
    int fp = (f >> 3) + (nwg >> 3) * (f & 7);
    if (yfast) { by = fp % ny; bx = (fp / ny) % nx; bz = fp / (ny * nx); }
    else       { bx = fp % nx; by = (fp / nx) % ny; bz = fp / (nx * ny); }
}

struct GemmArgs {
    const void* A;            // A source per AMODE
    const void* A2;           // second A source (fused projections)
    long long aStrideBytes;   // per-batch stride in BYTES
    int lda;                  // elements
    const u16* Bm;            // [N x K] bf16 (B^T layout)
    long long bStrideElts;
    int ldb;
    int K;                    // per-block K length
    const float* bias; const float* bias2; const float* bias3;
    u16* outB;                // bf16 output
    float* outF;              // fp32 output
    long long outFStride;     // per-batch elements
    const float* qm; const float* md; const float* tauPtr; float scale;
    // for LOGITS epilogue, qm/md carry eq = exp(-tau*qm), em = exp(-tau*md)
    float* partials;          // [B*2048 * 16] row partial sums
    const float* invsPtr;     // [8192] 1/rowsum (read, AMODE2)
    float* invsOut;           // [8192] 1/rowsum (written by PV norm blocks)
    u16* vt;                  // V transposed dest [B][512][2048]
};

enum { EPI_PROJ3 = 0, EPI_LOGITS = 1, EPI_LOGITSB = 2, EPI_PV = 3, EPI_OUT = 4 };
// AMODE: 0 = bf16 A via global_load_lds; 1 = fp32 A reg-stage+convert; 2 = sum of two
// bf16 split-K partials (+invs scale) reg-staged.
// U2: stage 2 BK=32 tiles per barrier pair (32 MFMA per vmcnt drain). AMODE=0 only.

template <int EPI, int AMODE, int TM, bool U2>
__global__ __launch_bounds__(256, 4) void gemm_bt(GemmArgs p) {
    constexpr int NB = U2 ? 2 : 1;
    constexpr int NF = (TM == 128) ? 4 : 2;
    __shared__ u16 As[NB][TM * 32];
    __shared__ u16 Bs[NB][128 * 32];
    __shared__ float redBuf[2][128];
    __shared__ float sInvLds[128];

    const int tid = threadIdx.x;
    const int lane = tid & 63;
    const int wave = tid >> 6;
    const int g = lane >> 4, lr = lane & 15;
    const int waveRowBase = (TM == 128) ? (wave >> 1) * 64 : 0;
    const int waveColBase = (TM == 128) ? (wave & 1) * 64 : wave * 32;

    int bxR = blockIdx.x, byR = blockIdx.y, bzR = blockIdx.z;
    // out-GEMM: y-fastest chunking (A-stripe reused across col-tiles on one XCD);
    // others: x-fastest (PV: one (batch,split) per XCD; logits: B-panel reuse).
    xcd_remap(bxR, byR, bzR, EPI == EPI_OUT);
    const int z = bzR;
    const int rowBase = bxR * TM;
    const int colBase = byR * 128;

    int batch = z, koff = 0;
    if constexpr (EPI == EPI_PV) { batch = z & 3; koff = (z >> 2) * p.K; }

    const char* Abase;
    const float* bias = p.bias;
    const u16* Bbase;
    if constexpr (EPI == EPI_PROJ3) {
        Abase = (const char*)(z == 0 ? p.A : p.A2);
        Bbase = p.Bm + (size_t)z * 512 * 512;
        bias = (z == 0) ? p.bias : (z == 1 ? p.bias2 : p.bias3);
    } else {
        Abase = (const char*)p.A + (size_t)batch * p.aStrideBytes + (size_t)koff * (AMODE == 1 ? 4 : 2);
        Bbase = p.Bm + (size_t)batch * p.bStrideElts + koff;
    }

    // ---- fused normalize + rowsum-inv blocks (PV big path, remapped y==4) ----
    if constexpr (EPI == EPI_PV && AMODE == 0) {
        if (byR == 4) {
            // 1/rowsum for rows [rowBase,+128)
            if (tid < 128) {
                const float* pp = p.partials + ((size_t)batch * 2048 + rowBase + tid) * 16;
                float s = 0.f;
                #pragma unroll
                for (int t = 0; t < 16; ++t) s += pp[t];
                float inv = 1.0f / s;
                sInvLds[tid] = inv;
                p.invsOut[batch * 2048 + rowBase + tid] = inv;  // both splits write same value
            }
            __syncthreads();
            const u16* e = (const u16*)Abase + (size_t)rowBase * 2048;
            float* attnOut = p.outF + (size_t)batch * p.outFStride + (size_t)rowBase * 2048 + koff;
            #pragma unroll 4
            for (int it = 0; it < 64; ++it) {
                int cc = it * 256 + tid;
                int row = cc >> 7, colc = (cc & 127) * 8;
                float s = sInvLds[row];
                u16x8 v = *(const u16x8*)(e + (size_t)row * 2048 + colc);
                f32x4 f0, f1;
                f0[0] = bf2f(v[0]) * s; f0[1] = bf2f(v[1]) * s;
                f0[2] = bf2f(v[2]) * s; f0[3] = bf2f(v[3]) * s;
                f1[0] = bf2f(v[4]) * s; f1[1] = bf2f(v[5]) * s;
                f1[2] = bf2f(v[6]) * s; f1[3] = bf2f(v[7]) * s;
                float* dst = attnOut + (size_t)row * 2048 + colc;
                __builtin_nontemporal_store(f0, (f32x4*)dst);
                __builtin_nontemporal_store(f1, (f32x4*)dst + 1);
            }
            return;
        }
    }

    f32x4 acc[4][NF] = {};

    // AMODE==2 invariants (hoisted)
    const int arow2 = tid >> 2, kh2 = (tid & 3) << 3;
    const u16* pa0 = nullptr; const u16* pa1 = nullptr; float sInv = 1.0f;
    if constexpr (AMODE == 2) {
        pa0 = (const u16*)p.A + (size_t)(rowBase + arow2) * 512 + kh2;
        pa1 = pa0 + (size_t)8192 * 512;
        sInv = p.invsPtr ? p.invsPtr[rowBase + arow2] : 1.0f;
    }

    const int nk = p.K >> 5;
    for (int kt = 0; kt < nk; kt += NB) {
        const int kb = kt << 5;
        float4 areg[4]; u16x8 a0, a1;
        if constexpr (AMODE == 1) {
            const float* Af = (const float*)Abase;
            const int arow = tid >> 1, kh = (tid & 1) << 4;
            const float* src = Af + (size_t)(rowBase + arow) * p.lda + kb + kh;
            #pragma unroll
            for (int j = 0; j < 4; ++j) areg[j] = ((const float4*)src)[j];
        } else if constexpr (AMODE == 2) {
            a0 = *(const u16x8*)(pa0 + kb);
            a1 = *(const u16x8*)(pa1 + kb);
        }
        __syncthreads();   // previous tiles fully consumed
        if constexpr (AMODE == 1) {
            const int arow = tid >> 1, kh = (tid & 1) << 4;
            u16 tmp[16];
            #pragma unroll
            for (int j = 0; j < 4; ++j) {
                tmp[4 * j + 0] = f2bf(areg[j].x);
                tmp[4 * j + 1] = f2bf(areg[j].y);
                tmp[4 * j + 2] = f2bf(areg[j].z);
                tmp[4 * j + 3] = f2bf(areg[j].w);
            }
            #pragma unroll
            for (int h = 0; h < 2; ++h)
                *(u16x8*)&As[0][arow * 32 + kh + h * 8] = *(u16x8*)&tmp[h * 8];
        } else if constexpr (AMODE == 2) {
            u16 tmp[8];
            #pragma unroll
            for (int j = 0; j < 8; ++j)
                tmp[j] = f2bf((bf2f(a0[j]) + bf2f(a1[j])) * sInv);
            *(u16x8*)&As[0][arow2 * 32 + kh2] = *(u16x8*)tmp;
        } else {
            #pragma unroll
            for (int b = 0; b < NB; ++b)
                #pragma unroll
                for (int i = 0; i < TM / 64; ++i) {
                    int c = i * 256 + tid;  // 16B chunks; row = c>>2, k-off = (c&3)*8
                    const u16* gp = (const u16*)Abase + (size_t)(rowBase + (c >> 2)) * p.lda + kb + b * 32 + (c & 3) * 8;
                    char* lp = (char*)&As[b][0] + (i * 256 + wave * 64) * 16;  // wave-uniform base
                    __builtin_amdgcn_global_load_lds((const __attribute__((address_space(1))) void*)gp,
                                                     (__attribute__((address_space(3))) void*)lp, 16, 0, 0);
                }
        }
        #pragma unroll
        for (int b = 0; b < NB; ++b)
            #pragma unroll
            for (int i = 0; i < 2; ++i) {
                int c = i * 256 + tid;
                const u16* gp = Bbase + (size_t)(colBase + (c >> 2)) * p.ldb + kb + b * 32 + (c & 3) * 8;
                char* lp = (char*)&Bs[b][0] + (i * 256 + wave * 64) * 16;
                __builtin_amdgcn_global_load_lds((const __attribute__((address_space(1))) void*)gp,
                                                 (__attribute__((address_space(3))) void*)lp, 16, 0, 0);
            }
        __syncthreads();   // staging complete (vmcnt drained by barrier)

        #pragma unroll
        for (int b = 0; b < NB; ++b) {
            bf16x8 af[4], bfr[NF];
            #pragma unroll
            for (int m = 0; m < 4; ++m)
                af[m] = *(const bf16x8*)&As[b][(waveRowBase + m * 16 + lr) * 32 + g * 8];
            #pragma unroll
            for (int n = 0; n < NF; ++n)
                bfr[n] = *(const bf16x8*)&Bs[b][(waveColBase + n * 16 + lr) * 32 + g * 8];
            #pragma unroll
            for (int m = 0; m < 4; ++m)
                #pragma unroll
                for (int n = 0; n < NF; ++n)
                    acc[m][n] = __builtin_amdgcn_mfma_f32_16x16x32_bf16(af[m], bfr[n], acc[m][n], 0, 0, 0);
        }
    }

    // epilogue: element (m,n,i): row = rB + m*16 + g*4 + i, col = cB + n*16 + lr
    const int rB = rowBase + waveRowBase;
    const int cB = colBase + waveColBase;

    if constexpr (EPI == EPI_PROJ3) {
        if (z < 2) {
            u16* dst = p.outB + (size_t)z * 8192 * 512;
            #pragma unroll
            for (int n = 0; n < NF; ++n) {
                int col = cB + n * 16 + lr;
                float bv = bias[col];
                #pragma unroll
                for (int m = 0; m < 4; ++m) {
                    int r0 = rB + m * 16 + g * 4;
                    #pragma unroll
                    for (int i = 0; i < 4; ++i)
                        dst[(size_t)(r0 + i) * 512 + col] = f2bf(acc[m][n][i] + bv);
                }
            }
        } else {  // V projection, transposed store
            #pragma unroll
            for (int n = 0; n < NF; ++n) {
                int col = cB + n * 16 + lr;
                float bv = bias[col];
                #pragma unroll
                for (int m = 0; m < 4; ++m) {
                    int r0 = rB + m * 16 + g * 4;
                    int b = r0 >> 11, k0 = r0 & 2047;
                    u16x4 pk;
                    #pragma unroll
                    for (int i = 0; i < 4; ++i) pk[i] = f2bf(acc[m][n][i] + bv);
                    *(u16x4*)&p.vt[((size_t)b * 512 + col) * 2048 + k0] = pk;
                }
            }
        }
    } else if constexpr (EPI == EPI_LOGITS || EPI == EPI_LOGITSB) {
        // u = sigmoid(tau*(qm+md)) = 1/(1 + eq*em), eq/em precomputed (rank-1)
        const float* eqB = p.qm + z * 2048;
        const float* emB = p.md + z * 2048;
        float* outRow = p.outF + (size_t)z * p.outFStride;
        float emv[NF];
        #pragma unroll
        for (int n = 0; n < NF; ++n) emv[n] = emB[cB + n * 16 + lr];
        #pragma unroll
        for (int m = 0; m < 4; ++m) {
            int r0 = rB + m * 16 + g * 4;
            #pragma unroll
            for (int i = 0; i < 4; ++i) {
                int q = r0 + i;
                float eqv = eqB[q];
                float rs = 0.f;
                #pragma unroll
                for (int n = 0; n < NF; ++n) {
                    float u = 1.0f / (1.0f + eqv * emv[n]);
                    u = fmaxf(u, 1e-6f);
                    float e = __expf(acc[m][n][i] * p.scale * u);
                    if (EPI == EPI_LOGITSB)
                        p.outB[((size_t)(z * 2048 + q)) * 2048 + cB + n * 16 + lr] = f2bf(e);
                    else
                        outRow[(size_t)q * 2048 + cB + n * 16 + lr] = e;
                    rs += e;
                }
                #pragma unroll
                for (int off = 1; off < 16; off <<= 1) rs += __shfl_xor(rs, off, 64);
                if (lr == 0) redBuf[wave & 1][waveRowBase + m * 16 + g * 4 + i] = rs;
            }
        }
        __syncthreads();
        if (tid < 128) {
            float s = redBuf[0][tid] + redBuf[1][tid];
            int q = rowBase + tid;
            p.partials[((size_t)z * 2048 + q) * 16 + byR] = s;
        }
    } else if constexpr (EPI == EPI_PV) {
        const int split = z >> 2;
        u16* dst = p.outB + (size_t)split * 8192 * 512;
        #pragma unroll
        for (int n = 0; n < NF; ++n) {
            int col = cB + n * 16 + lr;
            #pragma unroll
            for (int m = 0; m < 4; ++m) {
                int r0 = rB + m * 16 + g * 4;
                size_t gr = (size_t)batch * 2048 + r0;
                #pragma unroll
                for (int i = 0; i < 4; ++i)
                    dst[(gr + i) * 512 + col] = f2bf(acc[m][n][i]);
            }
        }
    } else {  // EPI_OUT (nontemporal: out is never re-read)
        #pragma unroll
        for (int n = 0; n < NF; ++n) {
            int col = cB + n * 16 + lr;
            float bv = p.bias[col];
            #pragma unroll
            for (int m = 0; m < 4; ++m) {
                int r0 = rB + m * 16 + g * 4;
                #pragma unroll
                for (int i = 0; i < 4; ++i)
                    __builtin_nontemporal_store(acc[m][n][i] + bv, &p.outF[(size_t)(r0 + i) * 512 + col]);
            }
        }
    }
}

// convert weights (4x 512x512) [+ qf/kf feats] to bf16; last 64 blocks compute
// eq = exp(-tau*qm), em = exp(-tau*md) (rank-1 sigmoid factors).
__global__ void cvt_all3(const float* Wq, const float* Wk, const float* Wv, const float* Wo,
                         const float* qf, const float* kf,
                         const float* qm, const float* md, const float* tauPtr,
                         u16* wdst, u16* qdst, u16* kdst,
                         float* eq, float* em) {
    if (blockIdx.x >= gridDim.x - 64) {
        int j = (blockIdx.x - (gridDim.x - 64)) * 256 + threadIdx.x;  // [0,16384)
        float tau = *tauPtr;
        if (j < 8192) eq[j] = __expf(-tau * qm[j]);
        else          em[j - 8192] = __expf(-tau * md[j - 8192]);
        return;
    }
    const size_t WSZ = (size_t)512 * 512;
    const size_t FSZ = (size_t)8192 * 512;
    size_t i = ((size_t)blockIdx.x * 256 + threadIdx.x) * 4;
    const float* src; u16* dstp;
    if (i < 4 * WSZ) {
        int w = (int)(i / WSZ);
        src = (w == 0 ? Wq : w == 1 ? Wk : w == 2 ? Wv : Wo) + (i - (size_t)w * WSZ);
        dstp = wdst + i;
    } else if (i < 4 * WSZ + FSZ) {
        size_t off = i - 4 * WSZ;
        src = qf + off; dstp = qdst + off;
    } else {
        size_t off = i - 4 * WSZ - FSZ;
        src = kf + off; dstp = kdst + off;
    }
    float4 v = *(const float4*)src;
    u16x4 u = { f2bf(v.x), f2bf(v.y), f2bf(v.z), f2bf(v.w) };
    *(u16x4*)dstp = u;
}

__global__ void rowsum_inv(const float* __restrict__ partials, float* __restrict__ invs) {
    int r = blockIdx.x * 256 + threadIdx.x;  // 8192 rows
    float s = 0.f;
    #pragma unroll
    for (int t = 0; t < 16; ++t) s += partials[r * 16 + t];
    invs[r] = 1.0f / s;
}

// fp32-e in-place normalize (small-ws fallback path)
__global__ void normalize_attn(float* __restrict__ attn, const float* __restrict__ invs) {
    size_t i4 = (size_t)blockIdx.x * 256 + threadIdx.x;  // 4 floats per thread
    int row = (int)(i4 >> 9);
    float s = invs[row];
    float4 v = ((const float4*)attn)[i4];
    v.x *= s; v.y *= s; v.z *= s; v.w *= s;
    ((float4*)attn)[i4] = v;
}

extern "C" void kernel_launch(void* const* d_in, const int* in_sizes, int n_in,
                              void* d_out, int out_size, void* d_ws, size_t ws_size,
                              hipStream_t stream) {
    const float* qf  = (const float*)d_in[0];
    const float* kf  = (const float*)d_in[1];
    const float* qm  = (const float*)d_in[2];
    const float* md  = (const float*)d_in[3];
    const float* Wq  = (const float*)d_in[4];
    const float* bq  = (const float*)d_in[5];
    const float* Wk  = (const float*)d_in[6];
    const float* bk  = (const float*)d_in[7];
    const float* Wv  = (const float*)d_in[8];
    const float* bv  = (const float*)d_in[9];
    const float* Wo  = (const float*)d_in[10];
    const float* bo  = (const float*)d_in[11];
    const float* tau = (const float*)d_in[12];

    float* out  = (float*)d_out;                       // [4,2048,512]
    float* attn = out + (size_t)4 * 2048 * 512;        // [4,2048,2048]

    const size_t NV = (size_t)8192 * 512;
    u16* Qb   = (u16*)d_ws;                            // [8192,512] bf16
    u16* Kb   = Qb + NV;
    u16* Vtb  = Kb + NV;                               // [4][512][2048]
    u16* Wqb  = Vtb + NV;                              // Wq,Wk,Wv,Wo bf16 contiguous
    u16* Wob  = Wqb + (size_t)3 * 512 * 512;
    float* partials = (float*)(Wqb + (size_t)4 * 512 * 512);  // [8192,16]
    float* invs = partials + (size_t)8192 * 16;
    float* eq = invs + 8192;                           // [8192] exp(-tau*qm)
    float* em = eq + 8192;                             // [8192] exp(-tau*md)
    u16* attE = (u16*)(em + 8192);                     // [4,2048,2048] bf16 (big path)
    u16* qfB  = attE + (size_t)4 * 2048 * 2048;        // [8192,512] bf16
    u16* kfB  = qfB + NV;
    size_t need = (size_t)((char*)(kfB + NV) - (char*)d_ws);
    const bool big = ws_size >= need;

    u16* partialPV = Qb;   // aliases Qb+Kb (dead after logits): [2][8192][512] bf16

    dim3 blk(256);

    GemmArgs a = {};
    a.lda = 512; a.ldb = 512; a.K = 512;
    a.bias = bq; a.bias2 = bk; a.bias3 = bv;
    a.outB = Qb; a.vt = Vtb;
    if (big) {
        // convert weights + feats to bf16 (+ eq/em), then fully-async projections
        cvt_all3<<<dim3(9280), blk, 0, stream>>>(Wq, Wk, Wv, Wo, qf, kf, qm, md, tau,
                                                 Wqb, qfB, kfB, eq, em);
        a.A = qfB; a.A2 = kfB; a.Bm = Wqb;
        gemm_bt<EPI_PROJ3, 0, 128, true><<<dim3(64, 4, 3), blk, 0, stream>>>(a);
    } else {
        cvt_all3<<<dim3(1088), blk, 0, stream>>>(Wq, Wk, Wv, Wo, qf, kf, qm, md, tau,
                                                 Wqb, nullptr, nullptr, eq, em);
        a.A = qf; a.A2 = kf; a.Bm = Wqb;
        gemm_bt<EPI_PROJ3, 1, 128, false><<<dim3(64, 4, 3), blk, 0, stream>>>(a);
    }

    // logits: e = exp((Q K^T)/sqrt(H) * u), u = 1/(1+eq*em); per-tile row partials
    GemmArgs lg = {};
    lg.A = Qb; lg.aStrideBytes = (long long)2048 * 512 * 2; lg.lda = 512;
    lg.Bm = Kb; lg.bStrideElts = (long long)2048 * 512; lg.ldb = 512;
    lg.K = 512;
    lg.qm = eq; lg.md = em; lg.tauPtr = tau;
    lg.scale = 0.04419417382415922f;  // 1/sqrt(512)
    lg.partials = partials;
    if (big) {
        lg.outB = attE;
        gemm_bt<EPI_LOGITSB, 0, 128, true><<<dim3(16, 16, 4), blk, 0, stream>>>(lg);
    } else {
        lg.outF = attn; lg.outFStride = (long long)2048 * 2048;
        gemm_bt<EPI_LOGITS, 0, 128, true><<<dim3(16, 16, 4), blk, 0, stream>>>(lg);
    }

    // att_partial[split] = e[., split*1024 : +1024] @ V  (split-K=2)
    // big path: remapped y==4 blocks compute invs + write normalized fp32 attn
    GemmArgs pv = {};
    pv.Bm = Vtb; pv.bStrideElts = (long long)512 * 2048; pv.ldb = 2048;
    pv.K = 1024; pv.outB = partialPV; pv.lda = 2048;
    pv.partials = partials; pv.invsOut = invs;
    if (big) {
        pv.A = attE; pv.aStrideBytes = (long long)2048 * 2048 * 2;
        pv.outF = attn; pv.outFStride = (long long)2048 * 2048;
        gemm_bt<EPI_PV, 0, 128, true><<<dim3(16, 5, 8), blk, 0, stream>>>(pv);
    } else {
        rowsum_inv<<<dim3(32), blk, 0, stream>>>(partials, invs);
        normalize_attn<<<dim3(16384), blk, 0, stream>>>(attn, invs);
        pv.A = attn; pv.aStrideBytes = (long long)2048 * 2048 * 4;
        gemm_bt<EPI_PV, 1, 128, false><<<dim3(16, 4, 8), blk, 0, stream>>>(pv);
    }

    // out = (partial0 + partial1)*invs @ Wo^T + bo  (reduce fused into A-stage)
    GemmArgs og = {};
    og.A = partialPV; og.lda = 512;
    og.Bm = Wob; og.ldb = 512;
    og.K = 512; og.bias = bo; og.outF = out;
    og.invsPtr = big ? invs : nullptr;
    gemm_bt<EPI_OUT, 2, 64, false><<<dim3(128, 4, 1), blk, 0, stream>>>(og);
}